// Round 8
// baseline (567.601 us; speedup 1.0000x reference)
//
#include <hip/hip_runtime.h>

constexpr int TAGS = 64;
constexpr int START_T = 62;
constexpr int END_T = 63;
constexpr float NEGF = -10000.0f;
constexpr int L_DIM = 512;
constexpr int B_DIM = 1024;

__device__ __forceinline__ float lane_bcast(float x, int lane) {
    return __int_as_float(__builtin_amdgcn_readlane(__float_as_int(x), lane));
}

__device__ __forceinline__ float wave_max64(float x) {
#pragma unroll
    for (int off = 32; off >= 1; off >>= 1)
        x = fmaxf(x, __shfl_xor(x, off, 64));
    return x;
}

__device__ __forceinline__ float wave_sum64(float x) {
#pragma unroll
    for (int off = 32; off >= 1; off >>= 1)
        x += __shfl_xor(x, off, 64);
    return x;
}

// One wave per block, one batch item per wave. lane = destination tag.
// Scan step: new[i] = feat[i] + M + log( sum_j E[i,j]*exp(alpha[j]-M) ),
// E = exp(transition) register-resident, v broadcast by v_readlane (VALU,
// SGPR dest). M = running wave-uniform offset (alpha[0]): any uniform M
// cancels exactly; finite alphas stay within ~+-10 of each other << 87.
//
// DESIGN HISTORY (do not regress):
//  R2 readlane matvec: 267us. Stalls traced to (a) wave-uniform mask load
//      scalarized to s_load -> cold ~900cy SMEM waits (fixed R6: mreg),
//      (b) allocator AGPR-shuffling Erow (fixed R3+: waves_per_eu(1)).
//  R3 LDS broadcast, no fence: RACED (post-timing absmax 96). Never write
//      then cross-lane-read LDS without an lgkmcnt drain.
//  R4 __syncthreads(): correct but drains vmcnt -> kills feats prefetch
//      every step (490us, VALU 13%).
//  R5/R6 minimal lgkmcnt fence + mreg: 225us, VALU 26% -> remaining stall
//      is raw ds_read latency (~120cy, several serialized groups) on the
//      serial chain at 1 wave/SIMD. LDS broadcast is the wrong tool here.
//  R7: pure-register broadcast. No LDS / no fence / no race in the loop;
//      matvec is ~128 pipelineable VALU instrs (issue-bound, latency-free).
//  (R7 submission hit GPUAcquisitionTimeout — resubmitted unchanged.)
__global__ __attribute__((amdgpu_waves_per_eu(1))) __launch_bounds__(64)
void crf_fused(
    const float* __restrict__ feats,
    const int* __restrict__ tags,
    const float* __restrict__ mask,
    const float* __restrict__ trans,
    float* __restrict__ out)
{
    __shared__ float sE[TAGS][TAGS + 2];             // staging only (not in loop)
    const int lane = threadIdx.x;                    // t_new
    const int b    = blockIdx.x;                     // batch item

    // Stage E = exp(transition) cooperatively (coalesced; precise expf).
#pragma unroll
    for (int k = 0; k < TAGS; ++k)
        sE[k][lane] = expf(trans[k * TAGS + lane]);  // exp(-10000) -> 0 exactly
    __syncthreads();

    // Each lane's E row -> 64 registers. waves_per_eu(1) gives the allocator
    // a 512-VGPR budget (no occupancy motive to evict); keep-alive asm stops
    // re-materialization as per-step LDS reads (R1: it did exactly that).
    float Erow[TAGS];
#pragma unroll
    for (int j = 0; j < TAGS; ++j) Erow[j] = sE[lane][j];
#pragma unroll
    for (int j = 0; j < TAGS; ++j) asm volatile("" : "+v"(Erow[j]));

    // Mask -> 8 per-lane registers (one-time). Kills ALL in-loop SMEM: a
    // wave-uniform __restrict__ mask load would be scalarized to s_load,
    // which counts in lgkmcnt and stalls the chain on cold HBM (R5 lesson).
    float mreg[L_DIM / 64];
#pragma unroll
    for (int k = 0; k < L_DIM / 64; ++k)
        mreg[k] = mask[(size_t)(64 * k + lane) * B_DIM + b];

    float a = (lane == START_T) ? 0.0f : NEGF;       // alpha0
    float M = 0.0f;                                  // true max of alpha0

    const float* fptr = feats + (size_t)b * TAGS + lane;
    const size_t fstride = (size_t)B_DIM * TAGS;

    // 4-deep feats prefetch (lane-strided vector global_loads, vmcnt-only).
    float f0 = fptr[0];
    float f1 = fptr[fstride];
    float f2 = fptr[2 * fstride];
    float f3 = fptr[3 * fstride];
    const float* fnext = fptr + 4 * fstride;         // rolling pointer: no per-step mul

#pragma unroll 1
    for (int k = 0; k < L_DIM / 64; ++k) {
        float mk = mreg[k];                          // once per 64 steps
#pragma unroll
        for (int j = 0; j < 64; ++j) {
            const int l = (k << 6) + j;
            float f4 = 0.0f;
            if (l + 4 < L_DIM) f4 = fnext[0];        // uniform branch, cheap
            fnext += fstride;
            float m0 = lane_bcast(mk, j);            // mask[l][b]: reg, 1 instr

            float v = __expf(a - M);                 // underflow->0 ok (incl START)

            float a0 = 0.f, a1 = 0.f, a2 = 0.f, a3 = 0.f;
#pragma unroll
            for (int t = 0; t < TAGS; t += 4) {      // 64x {readlane+fmac}: pure
                a0 = fmaf(Erow[t + 0], lane_bcast(v, t + 0), a0);   // register
                a1 = fmaf(Erow[t + 1], lane_bcast(v, t + 1), a1);   // dataflow,
                a2 = fmaf(Erow[t + 2], lane_bcast(v, t + 2), a2);   // no fence,
                a3 = fmaf(Erow[t + 3], lane_bcast(v, t + 3), a3);   // no race
            }
            float ssum = (a0 + a1) + (a2 + a3);

            float na = f0 + M + __logf(ssum);        // log(0) = -inf for START row
            na = fmaxf(na, -1e30f);                  // keep finite: -inf*0 = NaN
            a = na * m0 + a * (1.0f - m0);           // literal reference blend

            M = lane_bcast(a, 0);                    // running offset, 1 instr

            f0 = f1; f1 = f2; f2 = f3; f3 = f4;
        }
    }

    // allpath = LSE_i(alpha[i] + trans[END,i])  (one-time: exact max fine)
    float x = a + trans[END_T * TAGS + lane];
    float Mx = wave_max64(x);
    float ex = __expf(x - Mx);
    float S = wave_sum64(ex);
    float allp = Mx + __logf(S);

    // realpath: lanes split L (8 steps each), then wave-reduce.
    // mask for step lane+64k is exactly mreg[k] (same layout) — no reload.
    float sc = 0.0f, lensum = 0.0f;
#pragma unroll
    for (int k = 0; k < L_DIM / 64; ++k) {
        int l = lane + 64 * k;
        int tg = tags[l * B_DIM + b];
        int pv = (l == 0) ? START_T : tags[(l - 1) * B_DIM + b];
        float m = mreg[k];
        float emit = feats[((size_t)l * B_DIM + b) * TAGS + tg];
        float tr = trans[tg * TAGS + pv];
        sc += (emit + tr) * m;
        lensum += m;
    }
    sc = wave_sum64(sc);
    lensum = wave_sum64(lensum);
    int len = (int)lensum;                           // mask sum exact in fp32
    int last_tag = (len == 0) ? START_T : tags[(len - 1) * B_DIM + b];
    float realp = sc + trans[END_T * TAGS + last_tag];

    if (lane == 0) out[b] = allp - realp;
}

extern "C" void kernel_launch(void* const* d_in, const int* in_sizes, int n_in,
                              void* d_out, int out_size, void* d_ws, size_t ws_size,
                              hipStream_t stream) {
    const float* feats = (const float*)d_in[0];
    const int*   tags  = (const int*)d_in[1];
    const float* mask  = (const float*)d_in[2];
    const float* trans = (const float*)d_in[3];
    float* out = (float*)d_out;

    dim3 block(64, 1, 1);          // 1 wave per block
    dim3 grid(B_DIM, 1, 1);        // 1024 waves = 1 per SIMD across 256 CUs
    hipLaunchKernelGGL(crf_fused, grid, block, 0, stream,
                       feats, tags, mask, trans, out);
}

// Round 9
// 350.522 us; speedup vs baseline: 1.6193x; 1.6193x over previous
//
#include <hip/hip_runtime.h>

constexpr int TAGS = 64;
constexpr int START_T = 62;
constexpr int END_T = 63;
constexpr float NEGF = -10000.0f;
constexpr int L_DIM = 512;
constexpr int B_DIM = 1024;

__device__ __forceinline__ float lane_bcast(float x, int lane) {
    return __int_as_float(__builtin_amdgcn_readlane(__float_as_int(x), lane));
}

__device__ __forceinline__ float wave_max64(float x) {
#pragma unroll
    for (int off = 32; off >= 1; off >>= 1)
        x = fmaxf(x, __shfl_xor(x, off, 64));
    return x;
}

__device__ __forceinline__ float wave_sum64(float x) {
#pragma unroll
    for (int off = 32; off >= 1; off >>= 1)
        x += __shfl_xor(x, off, 64);
    return x;
}

// One wave per block, one batch item per wave. lane = destination tag.
// Scan step: new[i] = feat[i] + M + log( sum_j E[i,j]*exp(alpha[j]-M) ),
// E = exp(transition) register-resident, v broadcast by v_readlane.
// M = running wave-uniform offset (alpha[0]): any uniform M cancels exactly.
//
// DESIGN HISTORY (do not regress):
//  R2 readlane matvec, 267us: stalled on wave-uniform mask load scalarized
//      to s_load (~900cy cold SMEM on the chain). Fixed in R6 via mreg[].
//  R3 LDS broadcast, no fence: RACED (post-timing absmax 96).
//  R4 __syncthreads(): drains vmcnt -> kills feats prefetch (490us).
//  R5/R6 minimal lgkmcnt fence + mreg: 225us; remaining stall = raw
//      ds_read latency (~120cy) serialized on the chain at 1 wave/SIMD.
//  R7/R8 pure-register matvec BUT j-loop fully unrolled: body ~74KB >>
//      32KB I-cache -> instruction-fetch stalls, 470us. At 1 wave/SIMD,
//      CODE SIZE IS A LATENCY SURFACE: keep the loop body I-cache-resident.
//  R9: same instruction mix, j-loop unroll 2 -> ~2.4KB body.
__global__ __attribute__((amdgpu_waves_per_eu(1))) __launch_bounds__(64)
void crf_fused(
    const float* __restrict__ feats,
    const int* __restrict__ tags,
    const float* __restrict__ mask,
    const float* __restrict__ trans,
    float* __restrict__ out)
{
    __shared__ float sE[TAGS][TAGS + 2];             // staging only (not in loop)
    const int lane = threadIdx.x;                    // t_new
    const int b    = blockIdx.x;                     // batch item

    // Stage E = exp(transition) cooperatively (coalesced; precise expf).
#pragma unroll
    for (int k = 0; k < TAGS; ++k)
        sE[k][lane] = expf(trans[k * TAGS + lane]);  // exp(-10000) -> 0 exactly
    __syncthreads();

    // Each lane's E row -> 64 registers (waves_per_eu(1): 512-reg budget;
    // VALU sources AGPRs directly on gfx90a+ so AGPR placement is also fine).
    // Keep-alive asm stops re-materialization as per-step LDS reads (R1).
    float Erow[TAGS];
#pragma unroll
    for (int j = 0; j < TAGS; ++j) Erow[j] = sE[lane][j];
#pragma unroll
    for (int j = 0; j < TAGS; ++j) asm volatile("" : "+v"(Erow[j]));

    // Mask -> 8 per-lane registers (one-time). Kills ALL in-loop SMEM (a
    // wave-uniform __restrict__ mask load scalarizes to s_load, which counts
    // in lgkmcnt and sits cold-HBM on the serial chain — R5 lesson).
    float mreg[L_DIM / 64];
#pragma unroll
    for (int k = 0; k < L_DIM / 64; ++k)
        mreg[k] = mask[(size_t)(64 * k + lane) * B_DIM + b];

    float a = (lane == START_T) ? 0.0f : NEGF;       // alpha0
    float M = 0.0f;                                  // true max of alpha0

    const float* fptr = feats + (size_t)b * TAGS + lane;
    const size_t fstride = (size_t)B_DIM * TAGS;

    // 4-deep feats prefetch (lane-strided vector global_loads, vmcnt-only).
    float f0 = fptr[0];
    float f1 = fptr[fstride];
    float f2 = fptr[2 * fstride];
    float f3 = fptr[3 * fstride];
    const float* fnext = fptr + 4 * fstride;         // rolling ptr: no per-step mul

#pragma unroll 1
    for (int k = 0; k < L_DIM / 64; ++k) {           // k static -> mreg[k] stays
        float mk = mreg[k];                          //   in a register (rule #20)
#pragma unroll 2
        for (int j = 0; j < 64; ++j) {               // unroll 2: ~2.4KB body,
            const int l = (k << 6) + j;              //   I-cache-resident (R8!)
            float f4 = 0.0f;
            if (l + 4 < L_DIM) f4 = fnext[0];        // uniform branch, cheap
            fnext += fstride;
            float m0 = lane_bcast(mk, j);            // v_readlane w/ SGPR index

            float v = __expf(a - M);                 // underflow->0 ok (incl START)

            float a0 = 0.f, a1 = 0.f, a2 = 0.f, a3 = 0.f;
#pragma unroll
            for (int t = 0; t < TAGS; t += 4) {      // 64x {readlane+fmac}: pure
                a0 = fmaf(Erow[t + 0], lane_bcast(v, t + 0), a0);   // register
                a1 = fmaf(Erow[t + 1], lane_bcast(v, t + 1), a1);   // dataflow,
                a2 = fmaf(Erow[t + 2], lane_bcast(v, t + 2), a2);   // no fence,
                a3 = fmaf(Erow[t + 3], lane_bcast(v, t + 3), a3);   // no race
            }
            float ssum = (a0 + a1) + (a2 + a3);

            float na = f0 + M + __logf(ssum);        // log(0) = -inf for START row
            na = fmaxf(na, -1e30f);                  // keep finite: -inf*0 = NaN
            a = na * m0 + a * (1.0f - m0);           // literal reference blend

            M = lane_bcast(a, 0);                    // running offset, 1 instr

            f0 = f1; f1 = f2; f2 = f3; f3 = f4;
        }
    }

    // allpath = LSE_i(alpha[i] + trans[END,i])  (one-time: exact max fine)
    float x = a + trans[END_T * TAGS + lane];
    float Mx = wave_max64(x);
    float ex = __expf(x - Mx);
    float S = wave_sum64(ex);
    float allp = Mx + __logf(S);

    // realpath: lanes split L (8 steps each), then wave-reduce.
    // mask for step lane+64k is exactly mreg[k] (same layout) — no reload.
    float sc = 0.0f, lensum = 0.0f;
#pragma unroll
    for (int k = 0; k < L_DIM / 64; ++k) {
        int l = lane + 64 * k;
        int tg = tags[l * B_DIM + b];
        int pv = (l == 0) ? START_T : tags[(l - 1) * B_DIM + b];
        float m = mreg[k];
        float emit = feats[((size_t)l * B_DIM + b) * TAGS + tg];
        float tr = trans[tg * TAGS + pv];
        sc += (emit + tr) * m;
        lensum += m;
    }
    sc = wave_sum64(sc);
    lensum = wave_sum64(lensum);
    int len = (int)lensum;                           // mask sum exact in fp32
    int last_tag = (len == 0) ? START_T : tags[(len - 1) * B_DIM + b];
    float realp = sc + trans[END_T * TAGS + last_tag];

    if (lane == 0) out[b] = allp - realp;
}

extern "C" void kernel_launch(void* const* d_in, const int* in_sizes, int n_in,
                              void* d_out, int out_size, void* d_ws, size_t ws_size,
                              hipStream_t stream) {
    const float* feats = (const float*)d_in[0];
    const int*   tags  = (const int*)d_in[1];
    const float* mask  = (const float*)d_in[2];
    const float* trans = (const float*)d_in[3];
    float* out = (float*)d_out;

    dim3 block(64, 1, 1);          // 1 wave per block
    dim3 grid(B_DIM, 1, 1);        // 1024 waves = 1 per SIMD across 256 CUs
    hipLaunchKernelGGL(crf_fused, grid, block, 0, stream,
                       feats, tags, mask, trans, out);
}